// Round 1
// baseline (460.681 us; speedup 1.0000x reference)
//
#include <hip/hip_runtime.h>
#include <math.h>

// Problem constants
#define K_CODES 1024
#define C_DIM   128
#define HW      4096          // 64*64
#define CHW     (C_DIM*HW)    // per-batch stride in x
#define N_POS   65536         // 16*64*64
#define Q_ELEMS 8388608       // 16*128*64*64

// ws layout (byte offsets). Total use < 272 KB.
#define WS_S    0             // float: sum of sqrt(d2min) over all positions
#define WS_C2   256           // float[1024]: ||c_k||^2
#define WS_IDX  8192          // int[65536]: argmin index per position

// ---------------------------------------------------------------------------
// Kernel 1: codebook row squared norms; block 0 also zeroes the S accumulator
// (ws is re-poisoned to 0xAA before every launch).
// ---------------------------------------------------------------------------
__global__ void c2_kernel(const float* __restrict__ cb, float* __restrict__ ws) {
    int k = blockIdx.x;
    int l = threadIdx.x;                       // 64 lanes = 1 wave
    if (k == 0 && l == 0) *(float*)((char*)ws + WS_S) = 0.f;
    float v1 = cb[k * C_DIM + l];
    float v2 = cb[k * C_DIM + 64 + l];
    float ss = v1 * v1 + v2 * v2;
    #pragma unroll
    for (int off = 32; off > 0; off >>= 1) ss += __shfl_down(ss, off);
    if (l == 0) ((float*)((char*)ws + WS_C2))[k] = ss;
}

// ---------------------------------------------------------------------------
// Kernel 2: main VQ. 1024 blocks x 256 threads. Block = 64 positions of one
// batch image. Loop over 16 chunks of 64 codes. Thread tile: 16 pos x 1 code.
//   score(n,k) = c2[k] - 2*r[n]*(x_n . c_k);  d2min = 1 + min_k score
// LDS: xT[128][64] raw x tile (straight copy), cbT swizzled transpose chunk.
//   cbT word addr = c*64 + (k ^ ((c>>2)&31))  -> conflict-free writes & reads.
// ---------------------------------------------------------------------------
__global__ __launch_bounds__(256, 2) void vq_main(const float* __restrict__ x,
                                                  const float* __restrict__ cb,
                                                  float* __restrict__ ws) {
    __shared__ __align__(16) float xT[C_DIM * 64];   // [c][p]
    __shared__ __align__(16) float cbT[64 * C_DIM];  // swizzled [c][k]; first 64
                                                     // words double as r[] temp
    const float* c2w = (const float*)((char*)ws + WS_C2);
    int*  idxw = (int*)((char*)ws + WS_IDX);
    float* Sw  = (float*)((char*)ws + WS_S);

    const int t   = threadIdx.x;
    const int bid = blockIdx.x;
    const int b   = bid >> 6;          // batch
    const int s0  = (bid & 63) << 6;   // spatial tile start
    const int base = b * CHW + s0;     // fits in int (max 8.4M)

    // ---- stage x tile: 2048 float4, linear in both global rows and LDS ----
    {
        const float4* xg = (const float4*)x;
        float4* xs = (float4*)xT;
        const int b4 = base >> 2;
        #pragma unroll
        for (int i = 0; i < 8; ++i) {
            int u  = i * 256 + t;
            int c  = u >> 4;           // 16 float4 per 64-float row
            int p4 = u & 15;
            xs[u] = xg[b4 + c * 1024 + p4];   // 4096 floats / 4 = 1024
        }
    }
    __syncthreads();

    // ---- per-position inverse norms (wave 0), stashed in cbT[0..63] ----
    if (t < 64) {
        float ss = 0.f;
        #pragma unroll 8
        for (int c = 0; c < C_DIM; ++c) { float v = xT[c * 64 + t]; ss += v * v; }
        cbT[t] = 1.f / fmaxf(sqrtf(ss), 1e-12f);   // matches F.normalize eps
    }
    __syncthreads();

    const int pg = t >> 6;    // position group 0..3 (uniform per wave)
    const int kg = t & 63;    // code lane 0..63
    float rr[16];
    #pragma unroll
    for (int i = 0; i < 16; ++i) rr[i] = cbT[pg * 16 + i];
    __syncthreads();

    unsigned long long best[16];
    #pragma unroll
    for (int i = 0; i < 16; ++i) best[i] = ~0ULL;

    for (int chunk = 0; chunk < 16; ++chunk) {
        const int k0 = chunk << 6;
        // ---- stage codebook chunk, transposed + swizzled ----
        {
            const float4* cg = (const float4*)cb;
            #pragma unroll
            for (int i = 0; i < 8; ++i) {
                int u   = i * 256 + t;
                int row = u >> 5;          // code within chunk (0..63)
                int c4  = u & 31;          // float4 within 128-float row
                float4 v = cg[(k0 + row) * 32 + c4];
                int sw = row ^ c4;         // bank-spread swizzle
                cbT[(c4 * 4 + 0) * 64 + sw] = v.x;
                cbT[(c4 * 4 + 1) * 64 + sw] = v.y;
                cbT[(c4 * 4 + 2) * 64 + sw] = v.z;
                cbT[(c4 * 4 + 3) * 64 + sw] = v.w;
            }
        }
        __syncthreads();

        const float c2k = c2w[k0 + kg];
        float acc[16];
        #pragma unroll
        for (int i = 0; i < 16; ++i) acc[i] = 0.f;

        const float4* xsv = (const float4*)xT;
        #pragma unroll 4
        for (int c4 = 0; c4 < 32; ++c4) {
            const int kb = kg ^ c4;
            #pragma unroll
            for (int j = 0; j < 4; ++j) {
                const int c = c4 * 4 + j;
                float cbv = cbT[c * 64 + kb];
                float4 z0 = xsv[c * 16 + pg * 4 + 0];
                float4 z1 = xsv[c * 16 + pg * 4 + 1];
                float4 z2 = xsv[c * 16 + pg * 4 + 2];
                float4 z3 = xsv[c * 16 + pg * 4 + 3];
                acc[0]  += z0.x * cbv; acc[1]  += z0.y * cbv;
                acc[2]  += z0.z * cbv; acc[3]  += z0.w * cbv;
                acc[4]  += z1.x * cbv; acc[5]  += z1.y * cbv;
                acc[6]  += z1.z * cbv; acc[7]  += z1.w * cbv;
                acc[8]  += z2.x * cbv; acc[9]  += z2.y * cbv;
                acc[10] += z2.z * cbv; acc[11] += z2.w * cbv;
                acc[12] += z3.x * cbv; acc[13] += z3.y * cbv;
                acc[14] += z3.z * cbv; acc[15] += z3.w * cbv;
            }
        }

        // ---- score, pack (monotonic float bits | k), running min ----
        #pragma unroll
        for (int i = 0; i < 16; ++i) {
            float s = c2k - 2.f * rr[i] * acc[i];
            unsigned int fb   = __float_as_uint(s);
            unsigned int mono = fb ^ ((unsigned int)((int)fb >> 31) | 0x80000000u);
            unsigned long long u =
                ((unsigned long long)mono << 32) | (unsigned int)(k0 + kg);
            best[i] = (u < best[i]) ? u : best[i];
        }
        __syncthreads();   // before next chunk overwrites cbT
    }

    // ---- wave-wide argmin reduce (64 code lanes per wave) + loss partial ----
    float lsum = 0.f;
    #pragma unroll
    for (int i = 0; i < 16; ++i) {
        unsigned long long v = best[i];
        #pragma unroll
        for (int off = 32; off > 0; off >>= 1) {
            unsigned long long o = __shfl_down(v, off);
            v = (o < v) ? o : v;
        }
        if (kg == 0) {
            unsigned int mono = (unsigned int)(v >> 32);
            unsigned int fb = (mono & 0x80000000u) ? (mono ^ 0x80000000u) : ~mono;
            float smin = __uint_as_float(fb);
            float d2 = 1.0f + smin;                 // z2 == 1 after normalize
            lsum += sqrtf(fmaxf(d2, 0.f));
            idxw[bid * 64 + pg * 16 + i] = (int)(v & 0xFFFFFFFFu);
        }
    }
    if (kg == 0) atomicAdd(Sw, lsum);               // 4 atomics per block
}

// ---------------------------------------------------------------------------
// Kernel 3: scatter q = codebook[idx] back to [B,C,H,W], coalesced float4
// writes; codebook gathers hit L1/L2 (512 KB table).
// ---------------------------------------------------------------------------
__global__ void write_q(const float* __restrict__ cb,
                        const float* __restrict__ ws,
                        float* __restrict__ out) {
    const int* idxw = (const int*)((const char*)ws + WS_IDX);
    int e = blockIdx.x * 256 + threadIdx.x;   // float4 id, 2097152 total
    int f = e << 2;
    int s = f & 4095;
    int c = (f >> 12) & 127;
    int b = f >> 19;
    const int* ip = idxw + b * HW + s;
    float4 o;
    o.x = cb[ip[0] * C_DIM + c];
    o.y = cb[ip[1] * C_DIM + c];
    o.z = cb[ip[2] * C_DIM + c];
    o.w = cb[ip[3] * C_DIM + c];
    ((float4*)out)[e] = o;
}

// ---------------------------------------------------------------------------
// Kernel 4: finalize losses. loss = mean over N of sqrt(d2min); lw=(0.25, 1.0)
// ---------------------------------------------------------------------------
__global__ void fin_kernel(const float* __restrict__ ws, float* __restrict__ out) {
    float S = *(const float*)((const char*)ws + WS_S);
    float m = S / (float)N_POS;
    out[Q_ELEMS]     = 0.25f * m;
    out[Q_ELEMS + 1] = m;
}

extern "C" void kernel_launch(void* const* d_in, const int* in_sizes, int n_in,
                              void* d_out, int out_size, void* d_ws, size_t ws_size,
                              hipStream_t stream) {
    const float* x  = (const float*)d_in[0];   // [16,128,64,64]
    const float* cb = (const float*)d_in[1];   // [1024,128]
    float* out = (float*)d_out;
    float* ws  = (float*)d_ws;

    c2_kernel<<<K_CODES, 64, 0, stream>>>(cb, ws);
    vq_main<<<N_POS / 64, 256, 0, stream>>>(x, cb, ws);
    write_q<<<Q_ELEMS / 1024, 256, 0, stream>>>(cb, ws, out);
    fin_kernel<<<1, 1, 0, stream>>>(ws, out);
}

// Round 2
// 375.027 us; speedup vs baseline: 1.2284x; 1.2284x over previous
//
#include <hip/hip_runtime.h>
#include <math.h>

// Problem constants
#define K_CODES 1024
#define C_DIM   128
#define HW      4096          // 64*64
#define CHW     (C_DIM*HW)    // per-batch stride in x
#define N_POS   65536         // 16*64*64
#define Q_ELEMS 8388608       // 16*128*64*64

// ws layout (byte offsets). Total use < 272 KB (proven safe in round 1).
#define WS_S    0             // float: sum of sqrt(d2min)
#define WS_C2   256           // float[1024]: ||c_k||^2
#define WS_IDX  8192          // int[65536]: argmin index per position

// d_out used as scratch before write_q overwrites it (stream-ordered, safe):
#define QS_CBT  0             // float[131072]: cbT_g[c][k] transposed codebook
#define QS_R2   131072        // float[65536]: -2 / max(||x_p||, eps)

// ---------------------------------------------------------------------------
// Kernel 1: codebook row squared norms; block 0 zeroes the S accumulator.
// ---------------------------------------------------------------------------
__global__ void c2_kernel(const float* __restrict__ cb, float* __restrict__ ws) {
    int k = blockIdx.x;
    int l = threadIdx.x;                       // 64 lanes = 1 wave
    if (k == 0 && l == 0) *(float*)((char*)ws + WS_S) = 0.f;
    float v1 = cb[k * C_DIM + l];
    float v2 = cb[k * C_DIM + 64 + l];
    float ss = v1 * v1 + v2 * v2;
    #pragma unroll
    for (int off = 32; off > 0; off >>= 1) ss += __shfl_down(ss, off);
    if (l == 0) ((float*)((char*)ws + WS_C2))[k] = ss;
}

// ---------------------------------------------------------------------------
// Kernel 2: transpose codebook into d_out scratch: cbT_g[c][k] = cb[k][c]
// ---------------------------------------------------------------------------
__global__ void tr_kernel(const float* __restrict__ cb, float* __restrict__ qs) {
    int id = blockIdx.x * 256 + threadIdx.x;   // 131072 elements
    int k = id & 1023, c = id >> 10;
    qs[QS_CBT + id] = cb[k * C_DIM + c];       // coalesced writes
}

// ---------------------------------------------------------------------------
// Kernel 3: per-position r2 = -2 / max(||x_p||, eps)  (eps matches F.normalize)
// ---------------------------------------------------------------------------
__global__ void rnorm_kernel(const float* __restrict__ x, float* __restrict__ qs) {
    int p = blockIdx.x * 256 + threadIdx.x;    // 65536 positions
    int b = p >> 12, s = p & 4095;
    const float* xp = x + b * CHW + s;
    float ss = 0.f;
    #pragma unroll 8
    for (int c = 0; c < C_DIM; ++c) { float v = xp[c * HW]; ss = fmaf(v, v, ss); }
    qs[QS_R2 + p] = -2.0f / fmaxf(sqrtf(ss), 1e-12f);
}

// ---------------------------------------------------------------------------
// Kernel 4: main VQ. 512 blocks x 256 threads; block = 128 positions.
// LDS = cbT chunk only (64 KB) -> 2 blocks/CU (16 waves). Thread tile:
// 8 pos x 8 codes, as two 4-code sub-passes (acc stays at 32 VGPRs).
// x read from global per c (L1-resident 64 KB tile, TA pipe || LDS pipe).
//   score(p,k) = c2[k] + r2[p]*(x_p . c_k);  d2min = 1 + min_k score
// ---------------------------------------------------------------------------
__global__ __launch_bounds__(256, 4) void vq_main(const float* __restrict__ x,
                                                  const float* __restrict__ qs,
                                                  const float* __restrict__ c2w,
                                                  int* __restrict__ idxw,
                                                  float* __restrict__ Sw) {
    __shared__ __align__(16) float cbT[C_DIM * 128];   // [c][k-chunk] 64 KB

    const int t   = threadIdx.x;
    const int bid = blockIdx.x;
    const int cq  = t & 15;          // code quad 0..15
    const int pg  = t >> 4;          // pos group 0..15
    const int b   = bid >> 5;        // batch
    const int s0  = (bid & 31) << 7; // spatial tile start (128 wide)

    const float* xp = x + b * CHW + s0 + 4 * pg;   // lower-half pos base

    // per-position -2/norm for this thread's 8 positions (split tile: +0, +64)
    float4 r2a = *(const float4*)(qs + QS_R2 + bid * 128 + 4 * pg);
    float4 r2b = *(const float4*)(qs + QS_R2 + bid * 128 + 64 + 4 * pg);
    float r2v[8] = {r2a.x, r2a.y, r2a.z, r2a.w, r2b.x, r2b.y, r2b.z, r2b.w};

    unsigned long long best[8];
    #pragma unroll
    for (int i = 0; i < 8; ++i) best[i] = ~0ULL;

    for (int chunk = 0; chunk < 8; ++chunk) {
        __syncthreads();   // protect previous sub-pass reads
        // ---- stage 128-code chunk: dense float4 copy, conflict-free ----
        {
            const float4* src = (const float4*)(qs + QS_CBT);   // [c][1024]
            float4* dst = (float4*)cbT;
            const int cb4 = chunk << 5;      // chunk*128/4
            #pragma unroll
            for (int i = 0; i < 16; ++i) {
                int u  = i * 256 + t;        // float4 index in LDS (0..4095)
                int c  = u >> 5;             // row (128 floats = 32 float4)
                int q4 = u & 31;
                dst[u] = src[c * 256 + cb4 + q4];
            }
        }
        __syncthreads();

        #pragma unroll
        for (int h = 0; h < 2; ++h) {        // two 4-code sub-passes
            float acc[8][4];
            #pragma unroll
            for (int i = 0; i < 8; ++i)
                #pragma unroll
                for (int j = 0; j < 4; ++j) acc[i][j] = 0.f;

            const float* xc = xp;
            #pragma unroll 4
            for (int c = 0; c < C_DIM; ++c) {
                float4 cbv = *(const float4*)&cbT[c * 128 + h * 64 + 4 * cq];
                float4 x0  = *(const float4*)(xc);        // pos 4pg..+3
                float4 x1  = *(const float4*)(xc + 64);   // pos 64+4pg..+3
                xc += HW;
                float xv[8] = {x0.x, x0.y, x0.z, x0.w, x1.x, x1.y, x1.z, x1.w};
                float cv[4] = {cbv.x, cbv.y, cbv.z, cbv.w};
                #pragma unroll
                for (int i = 0; i < 8; ++i)
                    #pragma unroll
                    for (int j = 0; j < 4; ++j)
                        acc[i][j] = fmaf(xv[i], cv[j], acc[i][j]);
            }

            // ---- score + running min (pack monotonic bits | k) ----
            const int kbase = chunk * 128 + h * 64 + 4 * cq;
            float4 c2v = *(const float4*)(c2w + kbase);
            float c2j[4] = {c2v.x, c2v.y, c2v.z, c2v.w};
            #pragma unroll
            for (int i = 0; i < 8; ++i) {
                #pragma unroll
                for (int j = 0; j < 4; ++j) {
                    float s = fmaf(r2v[i], acc[i][j], c2j[j]);
                    unsigned int fb   = __float_as_uint(s);
                    unsigned int mono = fb ^ ((unsigned int)((int)fb >> 31) | 0x80000000u);
                    unsigned long long u =
                        ((unsigned long long)mono << 32) | (unsigned int)(kbase + j);
                    best[i] = (u < best[i]) ? u : best[i];
                }
            }
        }
    }

    // ---- cross-lane argmin over the 16 cq lanes sharing each position ----
    float lsum = 0.f;
    #pragma unroll
    for (int i = 0; i < 8; ++i) {
        unsigned long long v = best[i];
        #pragma unroll
        for (int m = 8; m >= 1; m >>= 1) {
            unsigned long long o = __shfl_xor(v, m);
            v = (o < v) ? o : v;
        }
        if (cq == 0) {
            unsigned int mono = (unsigned int)(v >> 32);
            unsigned int fb = (mono & 0x80000000u) ? (mono ^ 0x80000000u) : ~mono;
            float smin = __uint_as_float(fb);
            float d2 = 1.0f + smin;                       // z2 == 1 after normalize
            lsum += sqrtf(fmaxf(d2, 0.f));
            idxw[bid * 128 + 64 * (i >> 2) + 4 * pg + (i & 3)] =
                (int)(v & 0xFFFFFFFFu);
        }
    }
    if (cq == 0) atomicAdd(Sw, lsum);   // 16 atomics per block
}

// ---------------------------------------------------------------------------
// Kernel 5: scatter q = codebook[idx] back to [B,C,H,W] (overwrites scratch)
// ---------------------------------------------------------------------------
__global__ void write_q(const float* __restrict__ cb,
                        const float* __restrict__ ws,
                        float* __restrict__ out) {
    const int* idxw = (const int*)((const char*)ws + WS_IDX);
    int e = blockIdx.x * 256 + threadIdx.x;   // float4 id, 2097152 total
    int f = e << 2;
    int s = f & 4095;
    int c = (f >> 12) & 127;
    int b = f >> 19;
    const int* ip = idxw + b * HW + s;
    float4 o;
    o.x = cb[ip[0] * C_DIM + c];
    o.y = cb[ip[1] * C_DIM + c];
    o.z = cb[ip[2] * C_DIM + c];
    o.w = cb[ip[3] * C_DIM + c];
    ((float4*)out)[e] = o;
}

// ---------------------------------------------------------------------------
// Kernel 6: finalize losses. loss = mean over N of sqrt(d2min); lw=(0.25, 1.0)
// ---------------------------------------------------------------------------
__global__ void fin_kernel(const float* __restrict__ ws, float* __restrict__ out) {
    float S = *(const float*)((const char*)ws + WS_S);
    float m = S / (float)N_POS;
    out[Q_ELEMS]     = 0.25f * m;
    out[Q_ELEMS + 1] = m;
}

extern "C" void kernel_launch(void* const* d_in, const int* in_sizes, int n_in,
                              void* d_out, int out_size, void* d_ws, size_t ws_size,
                              hipStream_t stream) {
    const float* x  = (const float*)d_in[0];   // [16,128,64,64]
    const float* cb = (const float*)d_in[1];   // [1024,128]
    float* out = (float*)d_out;
    float* ws  = (float*)d_ws;

    const float* c2w = (const float*)((const char*)d_ws + WS_C2);
    int*  idxw = (int*)((char*)d_ws + WS_IDX);
    float* Sw  = (float*)((char*)d_ws + WS_S);

    c2_kernel   <<<K_CODES, 64, 0, stream>>>(cb, ws);
    tr_kernel   <<<512, 256, 0, stream>>>(cb, out);     // scratch in d_out
    rnorm_kernel<<<256, 256, 0, stream>>>(x, out);      // scratch in d_out
    vq_main     <<<N_POS / 128, 256, 0, stream>>>(x, out, c2w, idxw, Sw);
    write_q     <<<Q_ELEMS / 1024, 256, 0, stream>>>(cb, ws, out);
    fin_kernel  <<<1, 1, 0, stream>>>(ws, out);
}

// Round 3
// 166.092 us; speedup vs baseline: 2.7736x; 2.2579x over previous
//
#include <hip/hip_runtime.h>
#include <math.h>

// Problem constants
#define K_CODES 1024
#define C_DIM   128
#define HW      4096          // 64*64
#define CHW     (C_DIM*HW)    // per-batch stride in x
#define N_POS   65536         // 16*64*64
#define Q_ELEMS 8388608       // 16*128*64*64

// ws layout (byte offsets). Total 270336 B (proven safe in rounds 1-2).
#define WS_S    0             // float: sum of sqrt(d2min)
#define WS_C2   256           // float[1024]: ||c_k||^2
#define WS_IDX  8192          // u32[65536]: packed top-3 cand (stage1) -> final idx (stage2)

// d_out used as scratch before write_q overwrites it (stream-ordered, safe):
//   offset 0: bf16 codebook [k][c], 1024*128*2B = 256 KB

typedef __attribute__((ext_vector_type(8))) short short8;   // 8 bf16 (4 VGPRs)
typedef __attribute__((ext_vector_type(4))) float f32x4;    // MFMA acc

__device__ __forceinline__ unsigned short f2bf(float f) {   // fp32 -> bf16 RNE
    unsigned u = __float_as_uint(f);
    u += 0x7FFFu + ((u >> 16) & 1u);
    return (unsigned short)(u >> 16);
}

// ---------------------------------------------------------------------------
// Kernel 1: codebook row squared norms; block 0 zeroes the S accumulator.
// (identical to round 2 -> stage-2 scores replicate round-2 bitwise)
// ---------------------------------------------------------------------------
__global__ void c2_kernel(const float* __restrict__ cb, float* __restrict__ ws) {
    int k = blockIdx.x;
    int l = threadIdx.x;                       // 64 lanes = 1 wave
    if (k == 0 && l == 0) *(float*)((char*)ws + WS_S) = 0.f;
    float v1 = cb[k * C_DIM + l];
    float v2 = cb[k * C_DIM + 64 + l];
    float ss = v1 * v1 + v2 * v2;
    #pragma unroll
    for (int off = 32; off > 0; off >>= 1) ss += __shfl_down(ss, off);
    if (l == 0) ((float*)((char*)ws + WS_C2))[k] = ss;
}

// ---------------------------------------------------------------------------
// Kernel 2: codebook -> bf16 [k][c] into d_out scratch (256 KB)
// ---------------------------------------------------------------------------
__global__ void prep_cb(const float* __restrict__ cb, unsigned short* __restrict__ cbbf) {
    int id = blockIdx.x * 256 + threadIdx.x;   // 32768 threads x 4 elems
    float4 v = ((const float4*)cb)[id];
    ushort4 o;
    o.x = f2bf(v.x); o.y = f2bf(v.y); o.z = f2bf(v.z); o.w = f2bf(v.w);
    ((ushort4*)cbbf)[id] = o;
}

// ---------------------------------------------------------------------------
// Kernel 3: stage-1 MFMA scorer. 512 blocks x 256 thr; block = 128 positions,
// wave = 32 positions (2 pos-tiles of 16). Loop 16 chunks of 64 codes.
// A = codes (bf16 from LDS, dbuf), B = x positions (bf16 frags in regs,
// converted once from global). 16x16x32 bf16 MFMA (layouts m89/m118-verified).
// Keeps per-position top-3 approx candidates; exact rescore in stage 2.
// LDS: 2 x 17408 B (64 codes x 17-granule padded rows, conflict-free b128).
// ---------------------------------------------------------------------------
__global__ __launch_bounds__(256, 3) void vq_mfma(const float* __restrict__ x,
                                                  const unsigned short* __restrict__ cbbf,
                                                  const float* __restrict__ c2w,
                                                  unsigned int* __restrict__ candw) {
    __shared__ uint4 cbuf[2176];                // 2 x 1088 uint4 = 34816 B

    const int t  = threadIdx.x;
    const int w  = t >> 6;                      // wave 0..3
    const int ln = t & 63;
    const int lp = ln & 15;                     // m/n lane index
    const int q  = ln >> 4;                     // quad 0..3
    const int bid = blockIdx.x;
    const int b   = bid >> 5;                   // batch
    const int s0  = (bid & 31) << 7;            // spatial tile start (128 pos)

    // ---- x fragments (B operand): 2 pos-tiles x 4 k-steps, from global ----
    // B[k=8q+j + 32cs][n=lp]; 4 x 64B-aligned segments per load instr.
    short8 xf[2][4];
    float  r2v[2];
    {
        float ss[2] = {0.f, 0.f};
        #pragma unroll
        for (int pt = 0; pt < 2; ++pt) {
            const float* xgp = x + b * CHW + s0 + 32 * w + 16 * pt + lp;
            #pragma unroll
            for (int cs = 0; cs < 4; ++cs) {
                const float* xc = xgp + (32 * cs + 8 * q) * HW;
                union { short8 v; unsigned short u[8]; } fu;
                #pragma unroll
                for (int j = 0; j < 8; ++j) {
                    float vv = xc[j * HW];
                    ss[pt] = fmaf(vv, vv, ss[pt]);
                    fu.u[j] = f2bf(vv);
                }
                xf[pt][cs] = fu.v;
            }
        }
        #pragma unroll
        for (int pt = 0; pt < 2; ++pt) {        // combine quads -> full norm
            float s = ss[pt];
            s += __shfl_xor(s, 16);
            s += __shfl_xor(s, 32);
            r2v[pt] = -2.0f / fmaxf(sqrtf(s), 1e-12f);
        }
    }

    // ---- running top-3 (value,idx) per position ----
    float v1[2], v2[2], v3[2];
    int   i1[2], i2[2], i3[2];
    #pragma unroll
    for (int pt = 0; pt < 2; ++pt) {
        v1[pt] = v2[pt] = v3[pt] = __uint_as_float(0x7F7FFFFFu); // FLT_MAX
        i1[pt] = i2[pt] = i3[pt] = 0;
    }
    auto ins = [&](float v, int idx, int pt) {
        bool c1 = v < v1[pt], c2 = v < v2[pt], c3 = v < v3[pt];
        v3[pt] = c2 ? v2[pt] : (c3 ? v : v3[pt]);
        i3[pt] = c2 ? i2[pt] : (c3 ? idx : i3[pt]);
        v2[pt] = c1 ? v1[pt] : (c2 ? v : v2[pt]);
        i2[pt] = c1 ? i1[pt] : (c2 ? idx : i2[pt]);
        v1[pt] = c1 ? v : v1[pt];
        i1[pt] = c1 ? idx : i1[pt];
    };

    // ---- stage chunk 0: 1024 granules (16B), padded row stride 17 ----
    {
        const uint4* src4 = (const uint4*)cbbf;
        #pragma unroll
        for (int i = 0; i < 4; ++i) {
            int u = i * 256 + t;
            cbuf[(u >> 4) * 17 + (u & 15)] = src4[u];
        }
    }
    __syncthreads();

    for (int chunk = 0; chunk < 16; ++chunk) {
        const int k0 = chunk << 6;
        const bool more = chunk < 15;

        // prefetch next chunk (global -> regs)
        uint4 pre[4];
        if (more) {
            const uint4* src4 = (const uint4*)cbbf + (k0 + 64) * 16;
            #pragma unroll
            for (int i = 0; i < 4; ++i) pre[i] = src4[i * 256 + t];
        }

        // ---- MFMA: 4 code-tiles x 2 pos-tiles, K=128 in 4 steps ----
        f32x4 acc[4][2];
        #pragma unroll
        for (int ct = 0; ct < 4; ++ct)
            #pragma unroll
            for (int pt = 0; pt < 2; ++pt) acc[ct][pt] = 0;

        const unsigned short* cbp = (const unsigned short*)cbuf + (chunk & 1) * 8704;
        #pragma unroll
        for (int cs = 0; cs < 4; ++cs) {
            short8 ah[4];
            #pragma unroll
            for (int ct = 0; ct < 4; ++ct)   // A[m=lp][k=8q+j]: granule 4cs+q
                ah[ct] = *(const short8*)(cbp + ((16 * ct + lp) * 17 + 4 * cs + q) * 8);
            #pragma unroll
            for (int ct = 0; ct < 4; ++ct)
                #pragma unroll
                for (int pt = 0; pt < 2; ++pt)
                    acc[ct][pt] = __builtin_amdgcn_mfma_f32_16x16x32_bf16(
                        ah[ct], xf[pt][cs], acc[ct][pt], 0, 0, 0);
        }

        // write prefetched chunk into other buffer
        if (more) {
            uint4* dst = cbuf + ((chunk & 1) ^ 1) * 1088;
            #pragma unroll
            for (int i = 0; i < 4; ++i) {
                int u = i * 256 + t;
                dst[(u >> 4) * 17 + (u & 15)] = pre[i];
            }
        }

        // ---- epilogue: score + packed top-3 (6-bit local idx in low bits) ----
        unsigned m1[2] = {~0u, ~0u}, m2[2] = {~0u, ~0u}, m3[2] = {~0u, ~0u};
        #pragma unroll
        for (int ct = 0; ct < 4; ++ct) {
            float4 c2v = *(const float4*)(c2w + k0 + 16 * ct + 4 * q);
            float c2a[4] = {c2v.x, c2v.y, c2v.z, c2v.w};
            #pragma unroll
            for (int pt = 0; pt < 2; ++pt) {
                #pragma unroll
                for (int reg = 0; reg < 4; ++reg) {
                    float s = fmaf(r2v[pt], acc[ct][pt][reg], c2a[reg]);
                    unsigned fb   = __float_as_uint(s);
                    unsigned mono = fb ^ ((unsigned)((int)fb >> 31) | 0x80000000u);
                    unsigned uu = (mono & 0xFFFFFFC0u) | (unsigned)(16 * ct + 4 * q + reg);
                    unsigned t1 = max(m1[pt], uu); m1[pt] = min(m1[pt], uu);
                    unsigned t2 = max(m2[pt], t1); m2[pt] = min(m2[pt], t1);
                    m3[pt] = min(m3[pt], t2);
                }
            }
        }
        // merge chunk top-3 into running list (decode approx float + global idx)
        #pragma unroll
        for (int pt = 0; pt < 2; ++pt) {
            unsigned mm[3] = {m1[pt], m2[pt], m3[pt]};
            #pragma unroll
            for (int c = 0; c < 3; ++c) {
                unsigned m = mm[c];
                int idx = k0 + (int)(m & 63u);
                unsigned fb = (m & 0x80000000u) ? (m ^ 0x80000000u) : ~m;
                ins(__uint_as_float(fb), idx, pt);
            }
        }
        __syncthreads();
    }

    // ---- cross-lane merge over quads (lanes l, l^16, l^32) ----
    #pragma unroll
    for (int d = 16; d <= 32; d <<= 1) {
        #pragma unroll
        for (int pt = 0; pt < 2; ++pt) {
            float ov1 = __shfl_xor(v1[pt], d), ov2 = __shfl_xor(v2[pt], d),
                  ov3 = __shfl_xor(v3[pt], d);
            int   oi1 = __shfl_xor(i1[pt], d), oi2 = __shfl_xor(i2[pt], d),
                  oi3 = __shfl_xor(i3[pt], d);
            ins(ov1, oi1, pt); ins(ov2, oi2, pt); ins(ov3, oi3, pt);
        }
    }
    if (ln < 16) {
        #pragma unroll
        for (int pt = 0; pt < 2; ++pt) {
            int p = bid * 128 + 32 * w + 16 * pt + lp;
            candw[p] = (unsigned)i1[pt] | ((unsigned)i2[pt] << 10) |
                       ((unsigned)i3[pt] << 20);
        }
    }
}

// ---------------------------------------------------------------------------
// Kernel 4: stage-2 exact rescore (replicates round-2 fp32 math bitwise) +
// final idx + loss sum. One thread per position.
// ---------------------------------------------------------------------------
__global__ void rescore(const float* __restrict__ x, const float* __restrict__ cb,
                        const float* __restrict__ c2w,
                        unsigned int* __restrict__ idxw, float* __restrict__ Sw) {
    int p = blockIdx.x * 256 + threadIdx.x;
    int b = p >> 12, s = p & 4095;
    unsigned cand = idxw[p];
    int k1 = cand & 1023, k2 = (cand >> 10) & 1023, k3 = (cand >> 20) & 1023;
    const float* xp = x + b * CHW + s;
    const float* c1p = cb + k1 * C_DIM;
    const float* c2p = cb + k2 * C_DIM;
    const float* c3p = cb + k3 * C_DIM;
    float ss = 0.f, a1 = 0.f, a2 = 0.f, a3 = 0.f;
    #pragma unroll 8
    for (int c = 0; c < C_DIM; ++c) {
        float v = xp[c * HW];
        ss = fmaf(v, v, ss);
        a1 = fmaf(v, c1p[c], a1);
        a2 = fmaf(v, c2p[c], a2);
        a3 = fmaf(v, c3p[c], a3);
    }
    float r2 = -2.0f / fmaxf(sqrtf(ss), 1e-12f);
    float s1 = fmaf(r2, a1, c2w[k1]);
    float s2 = fmaf(r2, a2, c2w[k2]);
    float s3 = fmaf(r2, a3, c2w[k3]);
    float sb = s1; int kb = k1;
    if (s2 < sb || (s2 == sb && k2 < kb)) { sb = s2; kb = k2; }
    if (s3 < sb || (s3 == sb && k3 < kb)) { sb = s3; kb = k3; }
    idxw[p] = (unsigned)kb;
    float l = sqrtf(fmaxf(1.0f + sb, 0.f));
    #pragma unroll
    for (int off = 32; off > 0; off >>= 1) l += __shfl_down(l, off);
    if ((threadIdx.x & 63) == 0) atomicAdd(Sw, l);
}

// ---------------------------------------------------------------------------
// Kernel 5: scatter q = codebook[idx] back to [B,C,H,W] (overwrites scratch)
// ---------------------------------------------------------------------------
__global__ void write_q(const float* __restrict__ cb,
                        const float* __restrict__ ws,
                        float* __restrict__ out) {
    const int* idxw = (const int*)((const char*)ws + WS_IDX);
    int e = blockIdx.x * 256 + threadIdx.x;   // float4 id, 2097152 total
    int f = e << 2;
    int s = f & 4095;
    int c = (f >> 12) & 127;
    int b = f >> 19;
    const int* ip = idxw + b * HW + s;
    float4 o;
    o.x = cb[ip[0] * C_DIM + c];
    o.y = cb[ip[1] * C_DIM + c];
    o.z = cb[ip[2] * C_DIM + c];
    o.w = cb[ip[3] * C_DIM + c];
    ((float4*)out)[e] = o;
}

// ---------------------------------------------------------------------------
// Kernel 6: finalize losses. loss = mean over N of sqrt(d2min); lw=(0.25, 1.0)
// ---------------------------------------------------------------------------
__global__ void fin_kernel(const float* __restrict__ ws, float* __restrict__ out) {
    float S = *(const float*)((const char*)ws + WS_S);
    float m = S / (float)N_POS;
    out[Q_ELEMS]     = 0.25f * m;
    out[Q_ELEMS + 1] = m;
}

extern "C" void kernel_launch(void* const* d_in, const int* in_sizes, int n_in,
                              void* d_out, int out_size, void* d_ws, size_t ws_size,
                              hipStream_t stream) {
    const float* x  = (const float*)d_in[0];   // [16,128,64,64]
    const float* cb = (const float*)d_in[1];   // [1024,128]
    float* out = (float*)d_out;
    float* ws  = (float*)d_ws;

    const float* c2w = (const float*)((const char*)d_ws + WS_C2);
    unsigned int* idxw = (unsigned int*)((char*)d_ws + WS_IDX);
    float* Sw = (float*)((char*)d_ws + WS_S);
    unsigned short* cbbf = (unsigned short*)d_out;   // scratch in d_out

    c2_kernel<<<K_CODES, 64, 0, stream>>>(cb, ws);
    prep_cb  <<<128, 256, 0, stream>>>(cb, cbbf);
    vq_mfma  <<<N_POS / 128, 256, 0, stream>>>(x, cbbf, c2w, idxw);
    rescore  <<<N_POS / 256, 256, 0, stream>>>(x, cb, c2w, idxw, Sw);
    write_q  <<<Q_ELEMS / 1024, 256, 0, stream>>>(cb, ws, out);
    fin_kernel<<<1, 1, 0, stream>>>(ws, out);
}